// Round 7
// baseline (248.711 us; speedup 1.0000x reference)
//
#include <hip/hip_runtime.h>

// Newton-Schulz batched inverse, 1024 x (128x128) fp32.
// R7: TWO matrices per block (512 blocks -> 2 rounds), per-matrix 64KB LDS
// (T^T chunk-aliases xcm halves), W A-fragments pre-swizzled to global scratch
// (block-private 32KB slots in d_out; coalesced VMEM loads, off the LDS pipe),
// mm2 B-fragments reused across 2 tiles. hi-only bf16 X, XOR-swizzled LDS.

#define NN 128

typedef __attribute__((ext_vector_type(8))) short bf16x8;
typedef __attribute__((ext_vector_type(16))) float f32x16;
typedef __attribute__((ext_vector_type(4))) float f32x4;
typedef __attribute__((ext_vector_type(4))) unsigned short us4;

// LDS (bytes): 4 x 32KB bf16 buffers + 32KB fp32 half-stage = 160KB exactly.
#define XRA_OFF 0
#define XCA_OFF 32768
#define XRB_OFF 65536
#define XCB_OFF 98304
#define STG_OFF 131072
#define LDS_BYTES 163840
// red (2x256 f32) aliases xcA during sweep 1 (xcA filled only in sweep 2).

__device__ __forceinline__ unsigned short f2bf(float f) {
  unsigned u = __float_as_uint(f);
  return (unsigned short)((u + 0x7FFFu + ((u >> 16) & 1u)) >> 16);  // RNE
}
__device__ __forceinline__ float bf2f(unsigned short h) {
  return __uint_as_float(((unsigned)h) << 16);
}
__device__ __forceinline__ f32x16 zero16() {
  f32x16 z;
#pragma unroll
  for (int i = 0; i < 16; ++i) z[i] = 0.0f;
  return z;
}
// XOR swizzle in a [R][128] bf16 buffer: 8-elem granule g -> g ^ (R&7).
__device__ __forceinline__ int swz8(int R, int k0) {  // k0 % 8 == 0
  return R * 128 + (((k0 >> 3) ^ (R & 7)) << 3);
}
__device__ __forceinline__ int swz4(int R, int c0) {  // c0 % 4 == 0
  return R * 128 + ((((c0 >> 3) ^ (R & 7)) << 3) | (c0 & 7));
}
__device__ __forceinline__ int swz1(int R, int c) {
  return R * 128 + ((((c >> 3) ^ (R & 7)) << 3) | (c & 7));
}

__global__ void __launch_bounds__(1024)
ns_inverse_kernel(const float* __restrict__ Wglob, const int* __restrict__ nIt,
                  float* __restrict__ outglob) {
  extern __shared__ char lds[];
  float* stage = (float*)(lds + STG_OFF);
  float* red   = (float*)(lds + XCA_OFF);   // sweep-1 scratch only

  const int b = blockIdx.x;
  const int t = threadIdx.x;      // 0..1023
  const int lane = t & 63;
  const int wv = t >> 6;          // 0..15
  const int l31 = lane & 31;
  const int half = lane >> 5;
  const int Mw = wv >> 3;         // matrix 0/1 owned by this wave
  const int s  = wv & 3;          // strip: W rows / X' rows
  const int uu = (wv >> 2) & 1;   // 32-col offset within T chunk / 64-col X' band
  const int niters = nIt[0];

  // ---------------- sweep 1: norms (64-row half-stages) ----------------
  for (int M = 0; M < 2; ++M) {
    const float* Wm = Wglob + (size_t)(2 * b + M) * (NN * NN);
    for (int h = 0; h < 2; ++h) {
      const f32x4* src = (const f32x4*)(Wm + 8192 * h);
      f32x4* dst = (f32x4*)stage;
      dst[t] = src[t]; dst[t + 1024] = src[t + 1024];
      __syncthreads();
      if (t < 64) {               // full row sums for rows [64h..64h+64)
        float ss = 0.f;
        for (int jj = 0; jj < NN; ++jj) { int j = (jj + t) & 127; ss += fabsf(stage[t * NN + j]); }
        red[M * 256 + 64 * h + t] = ss;
      } else if (t >= 128 && t < 256) {   // partial col sums
        int c = t - 128;
        float ss = 0.f;
        for (int i = 0; i < 64; ++i) ss += fabsf(stage[i * NN + c]);
        red[M * 256 + 128 + c] = (h ? red[M * 256 + 128 + c] : 0.f) + ss;
      }
      __syncthreads();
    }
  }
  float scl2[2];
  for (int M = 0; M < 2; ++M) {
    float ninf = 0.f, n1 = 0.f;
    for (int i = 0; i < 128; ++i) {   // broadcast reads
      ninf = fmaxf(ninf, red[M * 256 + i]);
      n1   = fmaxf(n1,   red[M * 256 + 128 + i]);
    }
    scl2[M] = 1.0f / (n1 * ninf);
  }
  __syncthreads();   // red region free for xcA fill

  // ---------------- sweep 2: fills (re-stage, L2-hot) ----------------
  for (int M = 0; M < 2; ++M) {
    const float* Wm = Wglob + (size_t)(2 * b + M) * (NN * NN);
    unsigned short* xr = (unsigned short*)(lds + (M ? XRB_OFF : XRA_OFF));
    unsigned short* xc = (unsigned short*)(lds + (M ? XCB_OFF : XCA_OFF));
    unsigned short* dws = (unsigned short*)(outglob + (size_t)(2 * b + M) * (NN * NN));
    const float sc = scl2[M];
    for (int h = 0; h < 2; ++h) {
      const f32x4* src = (const f32x4*)(Wm + 8192 * h);
      f32x4* dst = (f32x4*)stage;
      dst[t] = src[t]; dst[t + 1024] = src[t + 1024];
      __syncthreads();
      {  // xc rows [64h..64h+64): X0 col n = W row n * scale
        int n = 64 * h + (t >> 4), c0 = (t & 15) * 8;
        const float* p = stage + (t >> 4) * NN + c0;
        f32x4 a = *(const f32x4*)p, bq = *(const f32x4*)(p + 4);
        us4 h0, h1;
#pragma unroll
        for (int i = 0; i < 4; ++i) { h0[i] = f2bf(a[i] * sc); h1[i] = f2bf(bq[i] * sc); }
        *(us4*)(xc + swz4(n, c0)) = h0;
        *(us4*)(xc + swz4(n, c0 + 4)) = h1;
      }
      {  // xr cols [64h..64h+64): X0 row r = W col r * scale (LDS transpose)
        int r = t & 127, j0 = (t >> 7) * 8;
        us4 h0, h1;
#pragma unroll
        for (int i = 0; i < 4; ++i) {
          h0[i] = f2bf(stage[(j0 + i) * NN + r] * sc);
          h1[i] = f2bf(stage[(j0 + 4 + i) * NN + r] * sc);
        }
        *(us4*)(xr + swz4(r, 64 * h + j0)) = h0;
        *(us4*)(xr + swz4(r, 64 * h + j0 + 4)) = h1;
      }
      {  // dws: pre-swizzled W A-fragments for rows [64h..64h+64) (unscaled)
        int sfr = 2 * h + ((t >> 9) & 1), ks = (t >> 6) & 7, ln = t & 63;
        int am = 32 * sfr + (ln & 31) - 64 * h;   // stage-local row
        int k0 = 16 * ks + 8 * (ln >> 5);
        const float* p = stage + am * NN + k0;
        f32x4 a = *(const f32x4*)p, bq = *(const f32x4*)(p + 4);
        bf16x8 f;
        f[0] = (short)f2bf(a[0]);  f[1] = (short)f2bf(a[1]);
        f[2] = (short)f2bf(a[2]);  f[3] = (short)f2bf(a[3]);
        f[4] = (short)f2bf(bq[0]); f[5] = (short)f2bf(bq[1]);
        f[6] = (short)f2bf(bq[2]); f[7] = (short)f2bf(bq[3]);
        *(bf16x8*)(dws + (size_t)((sfr * 8 + ks) * 64 + ln) * 8) = f;
      }
      __syncthreads();
    }
  }

  // ---------------- iterations: X' = 2X - X(WX), 2 matrices in lockstep ----
  unsigned short* xr = (unsigned short*)(lds + (Mw ? XRB_OFF : XRA_OFF));
  unsigned short* xc = (unsigned short*)(lds + (Mw ? XCB_OFF : XCA_OFF));
  const unsigned short* dws =
      (const unsigned short*)(outglob + (size_t)(2 * b + Mw) * (NN * NN));
  float* outm = outglob + (size_t)(2 * b + Mw) * (NN * NN);
  const int pX  = 32 * s + l31;     // lane-owned X/X' row
  const int rc0 = 32 * uu + l31;    // chunk-0 T col (xc row)

  for (int it = 0; it < niters; ++it) {
    const bool last = (it == niters - 1);

    // ---- mm1 chunk 0: T[32s.., 32uu..] ; A from dws (VMEM), B = xc[0:64) ----
    f32x16 tt0 = zero16();
#pragma unroll
    for (int ks = 0; ks < 8; ++ks) {
      bf16x8 av = *(const bf16x8*)(dws + (size_t)((s * 8 + ks) * 64 + lane) * 8);
      bf16x8 bv = *(const bf16x8*)(xc + swz8(rc0, 16 * ks + 8 * half));
      tt0 = __builtin_amdgcn_mfma_f32_32x32x16_bf16(av, bv, tt0, 0, 0, 0);
    }
    __syncthreads();   // B1: xc[0:64) consumed by all waves
#pragma unroll
    for (int q = 0; q < 4; ++q) {   // T^T chunk 0 -> xc rows [0:64)
      us4 h4;
#pragma unroll
      for (int i = 0; i < 4; ++i) h4[i] = f2bf(tt0[4 * q + i]);
      *(us4*)(xc + swz4(rc0, 32 * s + 8 * q + 4 * half)) = h4;
    }
    // ---- mm1 chunk 1: reads xc rows [64:128) (disjoint from Tw0) ----
    f32x16 tt1 = zero16();
#pragma unroll
    for (int ks = 0; ks < 8; ++ks) {
      bf16x8 av = *(const bf16x8*)(dws + (size_t)((s * 8 + ks) * 64 + lane) * 8);
      bf16x8 bv = *(const bf16x8*)(xc + swz8(64 + rc0, 16 * ks + 8 * half));
      tt1 = __builtin_amdgcn_mfma_f32_32x32x16_bf16(av, bv, tt1, 0, 0, 0);
    }
    __syncthreads();   // B2: xc[64:128) consumed; Tw0 visible
#pragma unroll
    for (int q = 0; q < 4; ++q) {   // T^T chunk 1 -> xc rows [64:128)
      us4 h4;
#pragma unroll
      for (int i = 0; i < 4; ++i) h4[i] = f2bf(tt1[4 * q + i]);
      *(us4*)(xc + swz4(64 + rc0, 32 * s + 8 * q + 4 * half)) = h4;
    }
    __syncthreads();   // B3: full T^T assembled in xc

    // ---- mm2: two tiles v=2uu, 2uu+1; B-fragments loaded once ----
    bf16x8 xb[8];
#pragma unroll
    for (int ks = 0; ks < 8; ++ks)
      xb[ks] = *(const bf16x8*)(xr + swz8(pX, 16 * ks + 8 * half));
    f32x16 a0 = zero16(), a1 = zero16();
#pragma unroll
    for (int ks = 0; ks < 8; ++ks) {
      int k0 = 16 * ks + 8 * half;
      bf16x8 av0 = *(const bf16x8*)(xc + swz8(64 * uu + l31, k0));
      bf16x8 av1 = *(const bf16x8*)(xc + swz8(64 * uu + 32 + l31, k0));
      a0 = __builtin_amdgcn_mfma_f32_32x32x16_bf16(av0, xb[ks], a0, 0, 0, 0);
      a1 = __builtin_amdgcn_mfma_f32_32x32x16_bf16(av1, xb[ks], a1, 0, 0, 0);
    }
    __syncthreads();   // B4: all mm2 xc/xr reads complete

    // ---- epilogue: X'[pX][32v+m] = 2X - (X@T), v = 2uu+j ----
#pragma unroll
    for (int j = 0; j < 2; ++j) {
      const f32x16 ac = j ? a1 : a0;
#pragma unroll
      for (int q = 0; q < 4; ++q) {
        int c0m = 32 * (2 * uu + j) + 8 * q + 4 * half;
        int offr = swz4(pX, c0m);
        us4 xh4 = *(const us4*)(xr + offr);
        f32x4 vv;
#pragma unroll
        for (int i = 0; i < 4; ++i)
          vv[i] = 2.0f * bf2f(xh4[i]) - ac[4 * q + i];
        if (last) {
          *(f32x4*)(outm + pX * NN + c0m) = vv;   // safe: all dws reads done
        } else {
          us4 h4;
#pragma unroll
          for (int i = 0; i < 4; ++i) {
            unsigned short hh = f2bf(vv[i]);
            h4[i] = hh;
            xc[swz1(c0m + i, pX)] = hh;   // X' col-major
          }
          *(us4*)(xr + offr) = h4;        // X' row-major
        }
      }
    }
    __syncthreads();   // B5: X' committed
  }
}

extern "C" void kernel_launch(void* const* d_in, const int* in_sizes, int n_in,
                              void* d_out, int out_size, void* d_ws, size_t ws_size,
                              hipStream_t stream) {
  const float* W = (const float*)d_in[0];
  const int* nIt = (const int*)d_in[1];
  float* out = (float*)d_out;
  const int nmat = in_sizes[0] / (NN * NN);   // 1024

  hipFuncSetAttribute((const void*)ns_inverse_kernel,
                      hipFuncAttributeMaxDynamicSharedMemorySize, LDS_BYTES);
  ns_inverse_kernel<<<nmat / 2, 1024, LDS_BYTES, stream>>>(W, nIt, out);
}

// Round 8
// 217.114 us; speedup vs baseline: 1.1455x; 1.1455x over previous
//
#include <hip/hip_runtime.h>

// Newton-Schulz batched inverse, 1024 x (128x128) fp32.
// R8: 512 thr / 1 matrix / block, 66.5KB LDS -> 2 blocks/CU (2 rounds).
// W lives as pre-swizzled bf16 MFMA fragments in GLOBAL scratch (VMEM pipe),
// xrm+xcm only in LDS; T^T chunk-aliases xcm (R4 5-barrier flow).
// Zero register arrays across the loop (R6 spill-free discipline).
// hi-only bf16 X (2d0-d1-d2 cancellation), XOR-swizzled conflict-free LDS.

#define NN 128

typedef __attribute__((ext_vector_type(8))) short bf16x8;
typedef __attribute__((ext_vector_type(16))) float f32x16;
typedef __attribute__((ext_vector_type(4))) float f32x4;
typedef __attribute__((ext_vector_type(4))) unsigned short us4;

// LDS (bytes): xrm [0,32768) X row-major; xcm [32768,65536) X col-major
// (T^T chunk c overwrites xcm rows [64c,64c+64) after consumption);
// red [65536,66560). fp32 W stage (64KB) aliases [0,65536), dead before fills.
#define XRM_OFF 0
#define XCM_OFF 32768
#define RED_OFF 65536
#define LDS_BYTES 66560

__device__ __forceinline__ unsigned short f2bf(float f) {
  unsigned u = __float_as_uint(f);
  return (unsigned short)((u + 0x7FFFu + ((u >> 16) & 1u)) >> 16);  // RNE
}
__device__ __forceinline__ float bf2f(unsigned short h) {
  return __uint_as_float(((unsigned)h) << 16);
}
__device__ __forceinline__ f32x16 zero16() {
  f32x16 z;
#pragma unroll
  for (int i = 0; i < 16; ++i) z[i] = 0.0f;
  return z;
}
// XOR swizzle in a [R][128] bf16 buffer: 8-elem granule g -> g ^ (R&7).
__device__ __forceinline__ int swz8(int R, int k0) {  // k0 % 8 == 0
  return R * 128 + (((k0 >> 3) ^ (R & 7)) << 3);
}
__device__ __forceinline__ int swz4(int R, int c0) {  // c0 % 4 == 0
  return R * 128 + ((((c0 >> 3) ^ (R & 7)) << 3) | (c0 & 7));
}
__device__ __forceinline__ int swz1(int R, int c) {
  return R * 128 + ((((c >> 3) ^ (R & 7)) << 3) | (c & 7));
}

__global__ void __launch_bounds__(512, 4)
ns_inverse_kernel(const float* __restrict__ Wglob, const int* __restrict__ nIt,
                  float* outglob, unsigned short* fragbase, int fragstride) {
  extern __shared__ char lds[];
  unsigned short* xrm = (unsigned short*)(lds + XRM_OFF);
  unsigned short* xcm = (unsigned short*)(lds + XCM_OFF);
  float* red   = (float*)(lds + RED_OFF);
  float* stage = (float*)lds;

  const int b = blockIdx.x;
  const float* Wg = Wglob + (size_t)b * (NN * NN);
  float* outg = outglob + (size_t)b * (NN * NN);
  unsigned short* frag = fragbase + (size_t)b * fragstride;
  const int t = threadIdx.x;      // 0..511
  const int lane = t & 63;
  const int wv = t >> 6;          // 0..7
  const int l31 = lane & 31;
  const int half = lane >> 5;
  const int s = wv & 3;           // strip: W rows (mm1 A) / X' rows
  const int u = wv >> 2;          // 32-col band within T chunk
  const int niters = nIt[0];

  // ---- phase 0: stage W fp32 into LDS ----
  {
    const f32x4* src = (const f32x4*)Wg;
    f32x4* dst = (f32x4*)stage;
#pragma unroll
    for (int i = 0; i < 8; ++i) dst[t + 512 * i] = src[t + 512 * i];
  }
  __syncthreads();

  // ---- norms ----
  if (t < 128) {            // row sums (rotated start)
    float ssum = 0.f;
    for (int jj = 0; jj < NN; ++jj) { int j = (jj + t) & 127; ssum += fabsf(stage[t * NN + j]); }
    red[t] = ssum;
  } else if (t < 256) {     // col sums
    int c = t - 128;
    float ssum = 0.f;
    for (int i = 0; i < NN; ++i) ssum += fabsf(stage[i * NN + c]);
    red[128 + c] = ssum;
  }
  __syncthreads();
  float ninf = 0.f, n1 = 0.f;
  for (int i = 0; i < 128; ++i) {   // broadcast reads
    ninf = fmaxf(ninf, red[i]);
    n1   = fmaxf(n1,   red[128 + i]);
  }
  const float scale = 1.0f / (n1 * ninf);

  // ---- pack W A-fragments to global scratch (frag idx = (sfr*8+ks)*64+ln) ----
#pragma unroll
  for (int j = 0; j < 4; ++j) {
    int idx = t * 4 + j;            // 0..2047
    int sfr = idx >> 9, ks = (idx >> 6) & 7, ln = idx & 63;
    int am = 32 * sfr + (ln & 31);
    int k0 = 16 * ks + 8 * (ln >> 5);
    const float* p = stage + am * NN + k0;
    f32x4 a = *(const f32x4*)p, bq = *(const f32x4*)(p + 4);
    bf16x8 f;
    f[0] = (short)f2bf(a[0]);  f[1] = (short)f2bf(a[1]);
    f[2] = (short)f2bf(a[2]);  f[3] = (short)f2bf(a[3]);
    f[4] = (short)f2bf(bq[0]); f[5] = (short)f2bf(bq[1]);
    f[6] = (short)f2bf(bq[2]); f[7] = (short)f2bf(bq[3]);
    *(bf16x8*)(frag + (size_t)idx * 8) = f;
  }
  __syncthreads();   // stage fully dead

  // ---- X0 fills from global (L2/L3-hot). X0 = W^T * scale ----
  // xcm row n = X0 col n = W row n (coalesced)
#pragma unroll
  for (int i = 0; i < 8; ++i) {
    int e0 = (t + 512 * i) * 4;
    int R = e0 >> 7, c0 = e0 & 127;
    f32x4 v = *(const f32x4*)(Wg + e0);
    us4 h4;
#pragma unroll
    for (int j = 0; j < 4; ++j) h4[j] = f2bf(v[j] * scale);
    *(us4*)(xcm + swz4(R, c0)) = h4;
  }
  // xrm row r = X0 row r = W col r (transpose read)
  {
    const int r = t & 127;
    const int kc = (t >> 7) * 32;
#pragma unroll
    for (int j4 = 0; j4 < 8; ++j4) {
      int c0 = kc + j4 * 4;
      us4 h4;
#pragma unroll
      for (int i = 0; i < 4; ++i) h4[i] = f2bf(Wg[(size_t)(c0 + i) * NN + r] * scale);
      *(us4*)(xrm + swz4(r, c0)) = h4;
    }
  }
  __syncthreads();

  // ---------------- iterations: X' = 2X - X(WX) ----------------
  const int pX = 32 * s + l31;          // lane-owned X row
  const int rr = 32 * u + l31;          // lane-owned T col (within chunk)
  for (int it = 0; it < niters; ++it) {
    const bool last = (it == niters - 1);

    // ---- mm1 c0: T cols [0,64) = W_strip @ X[:,0:64]; A from global frags ----
    {
      f32x16 t0 = zero16();
#pragma unroll
      for (int ks = 0; ks < 8; ++ks) {
        bf16x8 av = *(const bf16x8*)(frag + (size_t)((s * 8 + ks) * 64 + lane) * 8);
        bf16x8 bv = *(const bf16x8*)(xcm + swz8(rr, ks * 16 + half * 8));
        t0 = __builtin_amdgcn_mfma_f32_32x32x16_bf16(av, bv, t0, 0, 0, 0);
      }
      __syncthreads();   // B1: xcm rows [0,64) consumed by all waves
#pragma unroll
      for (int q = 0; q < 4; ++q) {   // T^T c0 -> xcm rows [0,64)
        us4 h4;
#pragma unroll
        for (int i = 0; i < 4; ++i) h4[i] = f2bf(t0[4 * q + i]);
        *(us4*)(xcm + swz4(rr, 32 * s + 8 * q + 4 * half)) = h4;
      }
    }
    // ---- mm1 c1: reads xcm rows [64,128) (disjoint from c0 writes) ----
    {
      f32x16 t1 = zero16();
#pragma unroll
      for (int ks = 0; ks < 8; ++ks) {
        bf16x8 av = *(const bf16x8*)(frag + (size_t)((s * 8 + ks) * 64 + lane) * 8);
        bf16x8 bv = *(const bf16x8*)(xcm + swz8(64 + rr, ks * 16 + half * 8));
        t1 = __builtin_amdgcn_mfma_f32_32x32x16_bf16(av, bv, t1, 0, 0, 0);
      }
      __syncthreads();   // B2: scrA visible; xcm rows [64,128) consumed
#pragma unroll
      for (int q = 0; q < 4; ++q) {   // T^T c1 -> xcm rows [64,128)
        us4 h4;
#pragma unroll
        for (int i = 0; i < 4; ++i) h4[i] = f2bf(t1[4 * q + i]);
        *(us4*)(xcm + 64 * 128 + swz4(rr, 32 * s + 8 * q + 4 * half)) = h4;
      }
    }
    __syncthreads();   // B3: full T^T assembled in xcm

    // ---- mm2: two tiles v = 2u+j; (X@T)^T rows [32v..), cols [32s..) ----
    f32x16 a0 = zero16(), a1 = zero16();
#pragma unroll
    for (int ks = 0; ks < 8; ++ks) {
      int k0 = ks * 16 + half * 8;
      bf16x8 bv  = *(const bf16x8*)(xrm + swz8(pX, k0));          // old X row
      bf16x8 av0 = *(const bf16x8*)(xcm + swz8(64 * u + l31, k0));
      bf16x8 av1 = *(const bf16x8*)(xcm + swz8(64 * u + 32 + l31, k0));
      a0 = __builtin_amdgcn_mfma_f32_32x32x16_bf16(av0, bv, a0, 0, 0, 0);
      a1 = __builtin_amdgcn_mfma_f32_32x32x16_bf16(av1, bv, a1, 0, 0, 0);
    }
    __syncthreads();   // B4: all mm2 xcm/xrm reads complete

    // ---- epilogue: X'[pX][32v+m] = 2X - (X@T), v = 2u+j ----
#pragma unroll
    for (int j = 0; j < 2; ++j) {
      const f32x16 ac = j ? a1 : a0;
#pragma unroll
      for (int q = 0; q < 4; ++q) {
        int c0m = 32 * (2 * u + j) + 8 * q + 4 * half;
        int offr = swz4(pX, c0m);
        us4 xh4 = *(const us4*)(xrm + offr);
        f32x4 vv;
#pragma unroll
        for (int i = 0; i < 4; ++i)
          vv[i] = 2.0f * bf2f(xh4[i]) - ac[4 * q + i];
        if (last) {
          *(f32x4*)(outg + pX * NN + c0m) = vv;  // frag reads all done (B3/B4)
        } else {
          us4 h4;
#pragma unroll
          for (int i = 0; i < 4; ++i) {
            unsigned short hh = f2bf(vv[i]);
            h4[i] = hh;
            xcm[swz1(c0m + i, pX)] = hh;   // X' col-major
          }
          *(us4*)(xrm + offr) = h4;        // X' row-major
        }
      }
    }
    __syncthreads();   // B5: X' committed
  }
}

extern "C" void kernel_launch(void* const* d_in, const int* in_sizes, int n_in,
                              void* d_out, int out_size, void* d_ws, size_t ws_size,
                              hipStream_t stream) {
  const float* W = (const float*)d_in[0];
  const int* nIt = (const int*)d_in[1];
  float* out = (float*)d_out;
  const int nmat = in_sizes[0] / (NN * NN);   // 1024

  // W-fragment scratch: d_ws if it fits, else block-private slots inside d_out
  // (safe: each block's frag reads complete before its last-iter out writes).
  unsigned short* fragbase;
  int fragstride;
  if (ws_size >= (size_t)nmat * NN * NN * sizeof(unsigned short)) {
    fragbase = (unsigned short*)d_ws;
    fragstride = NN * NN;          // 16384 bf16 = 32 KB per matrix
  } else {
    fragbase = (unsigned short*)d_out;
    fragstride = NN * NN * 2;      // first 32 KB of each matrix's 64 KB out slot
  }

  hipFuncSetAttribute((const void*)ns_inverse_kernel,
                      hipFuncAttributeMaxDynamicSharedMemorySize, LDS_BYTES);
  ns_inverse_kernel<<<nmat, 512, LDS_BYTES, stream>>>(W, nIt, out, fragbase, fragstride);
}